// Round 9
// baseline (226.894 us; speedup 1.0000x reference)
//
#include <hip/hip_runtime.h>

#define IMG_H 512
#define IMG_W 512
#define RH 32            // output rows per block; 34 input rows read
#define NBX (IMG_H / RH) // 16 row-blocks

// Round-9: attack the measured 262-cycle/row-step/CU invariant on both axes:
//  1. shfl halos: cols 2t-1 / 2t+2 come from neighbor lanes' float2 regs
//     (__shfl_up/down). Only wave-edge lanes (2/wave) do a clamped-address
//     scalar load; global borders are zeroed by a loop-invariant multiplier.
//     Loads/row: 6 -> 2 (+2-lane tiny); L1 line-services/step ~48 -> ~18.
//  2. two rows per step: 17 double-steps instead of 34 steps halves any
//     fixed per-step issue/wait overhead. Rolling 3-slot window unchanged
//     (slots advance 2/dstep; buffer x slot pattern has period 6 dsteps).
// Per-pixel math bit-identical to r8 (passed, absmax 0): same channels
// (n1,n2,nss,n12), same unscaled [1,RW,1] weights, same K2 scale, same
// per-thread accumulation order.

typedef float v2f __attribute__((ext_vector_type(2), aligned(8)));

__global__ __launch_bounds__(256) void ssim_main_kernel(
    const float* __restrict__ img1, const float* __restrict__ img2,
    double* __restrict__ partial)
{
    constexpr float W_E = 0.30780133f;  // f32-rounded Gaussian(sigma=1.5,k=3)
    constexpr float W_C = 0.38439734f;
    constexpr float RW = W_C / W_E;     // center/edge ratio
    constexpr float K2 = W_E * W_E;     // separable scale (applied in VOUT)
    constexpr float C1c = 1e-4f;
    constexpr float C2c = 9e-4f;

    const int t = threadIdx.x;
    const int y0 = blockIdx.x * RH;
    const size_t base = (size_t)blockIdx.y * (size_t)(IMG_H * IMG_W);
    const float* __restrict__ A = img1 + base;
    const float* __restrict__ B = img2 + base;
    const int x = 2 * t;

    // lane-role constants (loop-invariant)
    const bool isL = ((t & 63) == 0);          // needs left halo cross-wave
    const bool isR = ((t & 63) == 63);         // needs right halo cross-wave
    const bool isEdge = isL | isR;
    const float mE = (t == 0 || t == 255) ? 0.0f : 1.0f;  // global border mask
    const int hd = isL ? ((t == 0) ? 0 : -1)   // clamped halo offset (in-bounds)
                       : ((t == 255) ? 1 : 2);

    // rolling window of unscaled horizontal conv sums: [2 cols][3 row slots]
    float n1[2][3], n2[2][3], nss[2][3], n12[2][3];
    float tsum = 0.0f;

    v2f zz; zz.x = 0.0f; zz.y = 0.0f;

    // two double-row register buffers P,Q (+ edge-halo scalars per row)
    v2f Pa0, Pa1, Pb0, Pb1; float PhA0, PhB0, PhA1, PhB1;
    v2f Qa0, Qa1, Qb0, Qb1; float QhA0, QhB0, QhA1, QhB1;

    // load two rows (offset O, O+IMG_W) into buffer PRE; edge lanes also
    // fetch their halo scalar from the clamped, loop-invariant offset hd
#define LOADB(PRE, O) do {                                                    \
    PRE##a0 = *(const v2f*)(A + (O));                                         \
    PRE##b0 = *(const v2f*)(B + (O));                                         \
    PRE##a1 = *(const v2f*)(A + (O) + IMG_W);                                 \
    PRE##b1 = *(const v2f*)(B + (O) + IMG_W);                                 \
    if (isEdge) {                                                             \
        PRE##hA0 = (A + (O))[hd];          PRE##hB0 = (B + (O))[hd];          \
        PRE##hA1 = (A + (O) + IMG_W)[hd];  PRE##hB1 = (B + (O) + IMG_W)[hd];  \
    }                                                                         \
} while (0)

    // one input row -> horizontal 3-tap into slot S (r8-identical math);
    // halos via intra-wave shfl, wave-edge lanes via their scalar
#define HROW(RA, RB, HA, HB, S) do {                                          \
    float am_ = __shfl_up(RA.y, 1, 64);                                       \
    float ap_ = __shfl_down(RA.x, 1, 64);                                     \
    float bm_ = __shfl_up(RB.y, 1, 64);                                       \
    float bp_ = __shfl_down(RB.x, 1, 64);                                     \
    const float heA = (HA) * mE, heB = (HB) * mE;                             \
    am_ = isL ? heA : am_;  ap_ = isR ? heA : ap_;                            \
    bm_ = isL ? heB : bm_;  bp_ = isR ? heB : bp_;                            \
    const float a0_ = RA.x, a1_ = RA.y, b0_ = RB.x, b1_ = RB.y;               \
    const float ss0 = __builtin_fmaf(bm_, bm_, am_ * am_);                    \
    const float ss1 = __builtin_fmaf(b0_, b0_, a0_ * a0_);                    \
    const float ss2 = __builtin_fmaf(b1_, b1_, a1_ * a1_);                    \
    const float ss3 = __builtin_fmaf(bp_, bp_, ap_ * ap_);                    \
    const float p0 = am_ * bm_, p1 = a0_ * b0_;                               \
    const float p2 = a1_ * b1_, p3 = ap_ * bp_;                               \
    n1[0][S]  = __builtin_fmaf(RW, a0_, am_ + a1_);                           \
    n1[1][S]  = __builtin_fmaf(RW, a1_, a0_ + ap_);                           \
    n2[0][S]  = __builtin_fmaf(RW, b0_, bm_ + b1_);                           \
    n2[1][S]  = __builtin_fmaf(RW, b1_, b0_ + bp_);                           \
    nss[0][S] = __builtin_fmaf(RW, ss1, ss0 + ss2);                           \
    nss[1][S] = __builtin_fmaf(RW, ss2, ss1 + ss3);                           \
    n12[0][S] = __builtin_fmaf(RW, p1, p0 + p2);                              \
    n12[1][S] = __builtin_fmaf(RW, p2, p1 + p3);                              \
} while (0)

    // vertical unscaled 3-tap + K2 + SSIM (r8-identical)
#define VOUT(E0, E1, MID) do {                                                \
    _Pragma("unroll")                                                         \
    for (int c = 0; c < 2; ++c) {                                             \
        const float mu1 = K2 * __builtin_fmaf(RW, n1[c][MID],  n1[c][E0] + n1[c][E1]);  \
        const float mu2 = K2 * __builtin_fmaf(RW, n2[c][MID],  n2[c][E0] + n2[c][E1]);  \
        const float ess = K2 * __builtin_fmaf(RW, nss[c][MID], nss[c][E0] + nss[c][E1]);\
        const float e12 = K2 * __builtin_fmaf(RW, n12[c][MID], n12[c][E0] + n12[c][E1]);\
        const float mu1s = mu1 * mu1, mu2s = mu2 * mu2, m12 = mu1 * mu2;      \
        const float sss = (ess - mu1s) - mu2s;                                \
        const float s12 = e12 - m12;                                          \
        const float num = __builtin_fmaf(2.0f, m12, C1c) *                    \
                          __builtin_fmaf(2.0f, s12, C2c);                     \
        const float den = ((mu1s + mu2s) + C1c) * (sss + C2c);                \
        tsum += num / den;                                                    \
    }                                                                         \
} while (0)

    const size_t off = (size_t)y0 * IMG_W + x;  // row y0, col x

    // ---- prologue: P <- rows {y0-1 (guard top), y0}
    if (blockIdx.x != 0) {
        Pa0 = *(const v2f*)(A + off - IMG_W);
        Pb0 = *(const v2f*)(B + off - IMG_W);
        if (isEdge) { PhA0 = (A + off - IMG_W)[hd]; PhB0 = (B + off - IMG_W)[hd]; }
    } else { Pa0 = zz; Pb0 = zz; PhA0 = 0.f; PhB0 = 0.f; }
    Pa1 = *(const v2f*)(A + off);
    Pb1 = *(const v2f*)(B + off);
    if (isEdge) { PhA1 = (A + off)[hd]; PhB1 = (B + off)[hd]; }

    size_t o = off + IMG_W;  // next load: rows y0+1, y0+2 (i=2,3)

    // ---- d=0: load Q <- i(2,3); consume P (i=0 -> slot0, i=1 -> slot1)
    LOADB(Q, o); o += 2 * IMG_W;
    HROW(Pa0, Pb0, PhA0, PhB0, 0);
    HROW(Pa1, Pb1, PhA1, PhB1, 1);

    // ---- d=1..12: two groups of 6 dsteps (buffer x slot period = 6)
#pragma unroll 1
    for (int g = 0; g < 2; ++g) {
        // d%6==1: load P; consume Q (slots 2,0)
        LOADB(P, o); o += 2 * IMG_W;
        HROW(Qa0, Qb0, QhA0, QhB0, 2); VOUT(2, 0, 1);
        HROW(Qa1, Qb1, QhA1, QhB1, 0); VOUT(0, 1, 2);
        // d%6==2: load Q; consume P (slots 1,2)
        LOADB(Q, o); o += 2 * IMG_W;
        HROW(Pa0, Pb0, PhA0, PhB0, 1); VOUT(1, 2, 0);
        HROW(Pa1, Pb1, PhA1, PhB1, 2); VOUT(2, 0, 1);
        // d%6==3: load P; consume Q (slots 0,1)
        LOADB(P, o); o += 2 * IMG_W;
        HROW(Qa0, Qb0, QhA0, QhB0, 0); VOUT(0, 1, 2);
        HROW(Qa1, Qb1, QhA1, QhB1, 1); VOUT(1, 2, 0);
        // d%6==4: load Q; consume P (slots 2,0)
        LOADB(Q, o); o += 2 * IMG_W;
        HROW(Pa0, Pb0, PhA0, PhB0, 2); VOUT(2, 0, 1);
        HROW(Pa1, Pb1, PhA1, PhB1, 0); VOUT(0, 1, 2);
        // d%6==5: load P; consume Q (slots 1,2)
        LOADB(P, o); o += 2 * IMG_W;
        HROW(Qa0, Qb0, QhA0, QhB0, 1); VOUT(1, 2, 0);
        HROW(Qa1, Qb1, QhA1, QhB1, 2); VOUT(2, 0, 1);
        // d%6==0: load Q; consume P (slots 0,1)
        LOADB(Q, o); o += 2 * IMG_W;
        HROW(Pa0, Pb0, PhA0, PhB0, 0); VOUT(0, 1, 2);
        HROW(Pa1, Pb1, PhA1, PhB1, 1); VOUT(1, 2, 0);
    }

    // ---- d=13: load P <- i(28,29); consume Q (i=26,27 -> slots 2,0)
    LOADB(P, o); o += 2 * IMG_W;
    HROW(Qa0, Qb0, QhA0, QhB0, 2); VOUT(2, 0, 1);
    HROW(Qa1, Qb1, QhA1, QhB1, 0); VOUT(0, 1, 2);

    // ---- d=14: load Q <- i(30,31); consume P (i=28,29 -> slots 1,2)
    LOADB(Q, o); o += 2 * IMG_W;
    HROW(Pa0, Pb0, PhA0, PhB0, 1); VOUT(1, 2, 0);
    HROW(Pa1, Pb1, PhA1, PhB1, 2); VOUT(2, 0, 1);

    // ---- d=15: load P <- rows {y0+31, y0+32 (guard bottom)};
    //            consume Q (i=30,31 -> slots 0,1)
    Pa0 = *(const v2f*)(A + o);
    Pb0 = *(const v2f*)(B + o);
    if (isEdge) { PhA0 = (A + o)[hd]; PhB0 = (B + o)[hd]; }
    if (blockIdx.x != NBX - 1) {
        Pa1 = *(const v2f*)(A + o + IMG_W);
        Pb1 = *(const v2f*)(B + o + IMG_W);
        if (isEdge) { PhA1 = (A + o + IMG_W)[hd]; PhB1 = (B + o + IMG_W)[hd]; }
    } else { Pa1 = zz; Pb1 = zz; PhA1 = 0.f; PhB1 = 0.f; }
    HROW(Qa0, Qb0, QhA0, QhB0, 0); VOUT(0, 1, 2);
    HROW(Qa1, Qb1, QhA1, QhB1, 1); VOUT(1, 2, 0);

    // ---- d=16: consume P (i=32,33 -> slots 2,0)
    HROW(Pa0, Pb0, PhA0, PhB0, 2); VOUT(2, 0, 1);
    HROW(Pa1, Pb1, PhA1, PhB1, 0); VOUT(0, 1, 2);

#undef LOADB
#undef HROW
#undef VOUT

    // 64-lane wave reduction (f32, same order as before)
#pragma unroll
    for (int sft = 32; sft >= 1; sft >>= 1)
        tsum += __shfl_xor(tsum, sft, 64);

    __shared__ float wpart[4];
    if ((t & 63) == 0) wpart[t >> 6] = tsum;
    __syncthreads();
    if (t == 0) {
        partial[(size_t)blockIdx.y * gridDim.x + blockIdx.x] =
            (double)wpart[0] + (double)wpart[1] +
            (double)wpart[2] + (double)wpart[3];
    }
}

// Reduce 1536 per-block double partials -> out = 1 - sum. One block.
__global__ __launch_bounds__(256) void ssim_fin_kernel(
    const double* __restrict__ partial, float* __restrict__ out, int n)
{
    const int t = threadIdx.x;
    double s = 0.0;
    for (int i = t; i < n; i += 256) s += partial[i];
#pragma unroll
    for (int o = 32; o >= 1; o >>= 1)
        s += __shfl_xor(s, o, 64);
    __shared__ double w[4];
    if ((t & 63) == 0) w[t >> 6] = s;
    __syncthreads();
    if (t == 0)
        out[0] = 1.0f - (float)(w[0] + w[1] + w[2] + w[3]);
}

extern "C" void kernel_launch(void* const* d_in, const int* in_sizes, int n_in,
                              void* d_out, int out_size, void* d_ws, size_t ws_size,
                              hipStream_t stream) {
    const float* img1 = (const float*)d_in[0];
    const float* img2 = (const float*)d_in[1];
    float* out = (float*)d_out;
    double* partial = (double*)d_ws;  // needs 16*96*8 = 12288 B of workspace

    const int planes = in_sizes[0] / (IMG_H * IMG_W);  // 32*3 = 96

    dim3 grid(NBX, planes);
    ssim_main_kernel<<<grid, 256, 0, stream>>>(img1, img2, partial);
    ssim_fin_kernel<<<1, 256, 0, stream>>>(partial, out, NBX * planes);
}

// Round 10
// 224.844 us; speedup vs baseline: 1.0091x; 1.0091x over previous
//
#include <hip/hip_runtime.h>

#define IMG_H 512
#define IMG_W 512
#define RH 32            // output rows per block; 34 input rows read
#define NBX (IMG_H / RH) // 16 row-blocks

// Round-10: dense-stream version. Theory: all seven ~90us variants share one
// number — ~214 MB of L2-fill traffic at ~2.4 TB/s (L3-resident dispatches
// with FETCH~0 run at the SAME speed as 104-MB-HBM ones -> below-L3 delivery
// bound, not HBM). The D2D float4 copy reference sustains ~3.15 TB/s of
// read-stream. Make the kernel look like that stream:
//  - 1 thread = 4 ALIGNED cols: one 16B-aligned dwordx4 per image per row
//    (16 dense lines per wave-inst, zero overlap; r4 failed on MISalignment).
//  - halos via __shfl (r9-verified, bit-identical); 2 edge lanes/wave use
//    clamped scalar loads with loop-invariant offset + border mask.
//  - 128-thread blocks (2 waves); r9 proved 6 waves/CU saturate the limiter.
// Math/channels/skeleton are r8 verbatim (passed, absmax 0): unscaled
// [1,RW,1] taps, channels n1,n2,nss,n12, K2 scale in VOUT, same rotation.

typedef float v4f __attribute__((ext_vector_type(4), aligned(16)));

__global__ __launch_bounds__(128) void ssim_main_kernel(
    const float* __restrict__ img1, const float* __restrict__ img2,
    double* __restrict__ partial)
{
    constexpr float W_E = 0.30780133f;  // f32-rounded Gaussian(sigma=1.5,k=3)
    constexpr float W_C = 0.38439734f;
    constexpr float RW = W_C / W_E;     // center/edge ratio
    constexpr float K2 = W_E * W_E;     // separable scale (applied in VOUT)
    constexpr float C1c = 1e-4f;
    constexpr float C2c = 9e-4f;

    const int t = threadIdx.x;          // 0..127, owns cols 4t..4t+3
    const int y0 = blockIdx.x * RH;
    const size_t base = (size_t)blockIdx.y * (size_t)(IMG_H * IMG_W);
    const float* __restrict__ A = img1 + base;
    const float* __restrict__ B = img2 + base;
    const int x = 4 * t;

    // lane-role constants (loop-invariant)
    const bool isL = ((t & 63) == 0);            // t = 0, 64: left halo cross-wave
    const bool isR = ((t & 63) == 63);           // t = 63, 127: right halo cross-wave
    const bool isEdge = isL | isR;
    const float mE = (t == 0 || t == 127) ? 0.0f : 1.0f;   // global border -> zero
    const int hd = isL ? ((t == 0) ? 0 : -1)     // clamped in-bounds halo offset
                       : ((t == 127) ? 1 : 4);

    // rolling window of unscaled horizontal conv sums: [4 cols][3 row slots]
    float n1[4][3], n2[4][3], nss[4][3], n12[4][3];
    float tsum = 0.0f;

    // two single-row register buffers (one float4 per image + edge scalars)
    v4f Pa, Pb; float PhA, PhB;
    v4f Qa, Qb; float QhA, QhB;

#define LOADROW(V, OFF) do {                                                  \
    V##a = *(const v4f*)(A + (OFF));                                          \
    V##b = *(const v4f*)(B + (OFF));                                          \
    if (isEdge) { V##hA = (A + (OFF))[hd]; V##hB = (B + (OFF))[hd]; }         \
} while (0)

#define ZEROROW(V) do {                                                       \
    V##a.x = 0.f; V##a.y = 0.f; V##a.z = 0.f; V##a.w = 0.f;                   \
    V##b.x = 0.f; V##b.y = 0.f; V##b.z = 0.f; V##b.w = 0.f;                   \
    V##hA = 0.f;  V##hB = 0.f;                                                \
} while (0)

    // one input row -> horizontal 3-tap into slot S for the 4 owned cols;
    // halos via intra-wave shfl, wave-edge lanes via clamped scalar
#define HPASS(V, S) do {                                                      \
    float al_ = __shfl_up(V##a.w, 1, 64);                                     \
    float ar_ = __shfl_down(V##a.x, 1, 64);                                   \
    float bl_ = __shfl_up(V##b.w, 1, 64);                                     \
    float br_ = __shfl_down(V##b.x, 1, 64);                                   \
    const float heA = V##hA * mE, heB = V##hB * mE;                           \
    al_ = isL ? heA : al_;  ar_ = isR ? heA : ar_;                            \
    bl_ = isL ? heB : bl_;  br_ = isR ? heB : br_;                            \
    const float ea0 = al_, ea1 = V##a.x, ea2 = V##a.y;                        \
    const float ea3 = V##a.z, ea4 = V##a.w, ea5 = ar_;                        \
    const float eb0 = bl_, eb1 = V##b.x, eb2 = V##b.y;                        \
    const float eb3 = V##b.z, eb4 = V##b.w, eb5 = br_;                        \
    const float ss0 = __builtin_fmaf(eb0, eb0, ea0 * ea0);                    \
    const float ss1 = __builtin_fmaf(eb1, eb1, ea1 * ea1);                    \
    const float ss2 = __builtin_fmaf(eb2, eb2, ea2 * ea2);                    \
    const float ss3 = __builtin_fmaf(eb3, eb3, ea3 * ea3);                    \
    const float ss4 = __builtin_fmaf(eb4, eb4, ea4 * ea4);                    \
    const float ss5 = __builtin_fmaf(eb5, eb5, ea5 * ea5);                    \
    const float p0 = ea0 * eb0, p1 = ea1 * eb1, p2 = ea2 * eb2;               \
    const float p3 = ea3 * eb3, p4 = ea4 * eb4, p5 = ea5 * eb5;               \
    n1[0][S]  = __builtin_fmaf(RW, ea1, ea0 + ea2);                           \
    n1[1][S]  = __builtin_fmaf(RW, ea2, ea1 + ea3);                           \
    n1[2][S]  = __builtin_fmaf(RW, ea3, ea2 + ea4);                           \
    n1[3][S]  = __builtin_fmaf(RW, ea4, ea3 + ea5);                           \
    n2[0][S]  = __builtin_fmaf(RW, eb1, eb0 + eb2);                           \
    n2[1][S]  = __builtin_fmaf(RW, eb2, eb1 + eb3);                           \
    n2[2][S]  = __builtin_fmaf(RW, eb3, eb2 + eb4);                           \
    n2[3][S]  = __builtin_fmaf(RW, eb4, eb3 + eb5);                           \
    nss[0][S] = __builtin_fmaf(RW, ss1, ss0 + ss2);                           \
    nss[1][S] = __builtin_fmaf(RW, ss2, ss1 + ss3);                           \
    nss[2][S] = __builtin_fmaf(RW, ss3, ss2 + ss4);                           \
    nss[3][S] = __builtin_fmaf(RW, ss4, ss3 + ss5);                           \
    n12[0][S] = __builtin_fmaf(RW, p1, p0 + p2);                              \
    n12[1][S] = __builtin_fmaf(RW, p2, p1 + p3);                              \
    n12[2][S] = __builtin_fmaf(RW, p3, p2 + p4);                              \
    n12[3][S] = __builtin_fmaf(RW, p4, p3 + p5);                              \
} while (0)

    // vertical unscaled 3-tap + K2 + SSIM (r8-identical per pixel)
#define VOUT(E0, E1, MID) do {                                                \
    _Pragma("unroll")                                                         \
    for (int c = 0; c < 4; ++c) {                                             \
        const float mu1 = K2 * __builtin_fmaf(RW, n1[c][MID],  n1[c][E0] + n1[c][E1]);  \
        const float mu2 = K2 * __builtin_fmaf(RW, n2[c][MID],  n2[c][E0] + n2[c][E1]);  \
        const float ess = K2 * __builtin_fmaf(RW, nss[c][MID], nss[c][E0] + nss[c][E1]);\
        const float e12 = K2 * __builtin_fmaf(RW, n12[c][MID], n12[c][E0] + n12[c][E1]);\
        const float mu1s = mu1 * mu1, mu2s = mu2 * mu2, m12 = mu1 * mu2;      \
        const float sss = (ess - mu1s) - mu2s;                                \
        const float s12 = e12 - m12;                                          \
        const float num = __builtin_fmaf(2.0f, m12, C1c) *                    \
                          __builtin_fmaf(2.0f, s12, C2c);                     \
        const float den = ((mu1s + mu2s) + C1c) * (sss + C2c);                \
        tsum += num / den;                                                    \
    }                                                                         \
} while (0)

    size_t off = (size_t)y0 * IMG_W + x;  // element offset of row y0, col x

    // i=0: input row y0-1 -> P (zeros above the image; uniform branch)
    if (blockIdx.x != 0) LOADROW(P, off - IMG_W); else ZEROROW(P);
    // prefetch i=1: row y0 -> Q
    LOADROW(Q, off);
    HPASS(P, 0);
    // i=1: prefetch row y0+1 -> P; consume Q into slot 1
    LOADROW(P, off + IMG_W);
    HPASS(Q, 1);
    off += 2 * (size_t)IMG_W;  // next row to load: y0+2

    // middle steps i=2..31: 5 groups of 6 (period lcm(3,2)); step i loads
    // row y0+i (all interior), consumes the row loaded two steps ago.
#pragma unroll 1
    for (int g = 0; g < 5; ++g) {
        LOADROW(Q, off); off += IMG_W; HPASS(P, 2); VOUT(2, 0, 1);
        LOADROW(P, off); off += IMG_W; HPASS(Q, 0); VOUT(0, 1, 2);
        LOADROW(Q, off); off += IMG_W; HPASS(P, 1); VOUT(1, 2, 0);
        LOADROW(P, off); off += IMG_W; HPASS(Q, 2); VOUT(2, 0, 1);
        LOADROW(Q, off); off += IMG_W; HPASS(P, 0); VOUT(0, 1, 2);
        LOADROW(P, off); off += IMG_W; HPASS(Q, 1); VOUT(1, 2, 0);
    }

    // i=32: consume P slot 2; prefetch last input row y0+32 (zeros below image)
    if (blockIdx.x != NBX - 1) LOADROW(Q, off); else ZEROROW(Q);
    HPASS(P, 2); VOUT(2, 0, 1);
    // i=33: consume Q slot 0
    HPASS(Q, 0); VOUT(0, 1, 2);

#undef LOADROW
#undef ZEROROW
#undef HPASS
#undef VOUT

    // 64-lane wave reduction; 2 waves per block
#pragma unroll
    for (int o = 32; o >= 1; o >>= 1)
        tsum += __shfl_xor(tsum, o, 64);

    __shared__ float wpart[2];
    if ((t & 63) == 0) wpart[t >> 6] = tsum;
    __syncthreads();
    if (t == 0) {
        partial[(size_t)blockIdx.y * gridDim.x + blockIdx.x] =
            (double)wpart[0] + (double)wpart[1];
    }
}

// Reduce 1536 per-block double partials -> out = 1 - sum. One block.
__global__ __launch_bounds__(256) void ssim_fin_kernel(
    const double* __restrict__ partial, float* __restrict__ out, int n)
{
    const int t = threadIdx.x;
    double s = 0.0;
    for (int i = t; i < n; i += 256) s += partial[i];
#pragma unroll
    for (int o = 32; o >= 1; o >>= 1)
        s += __shfl_xor(s, o, 64);
    __shared__ double w[4];
    if ((t & 63) == 0) w[t >> 6] = s;
    __syncthreads();
    if (t == 0)
        out[0] = 1.0f - (float)(w[0] + w[1] + w[2] + w[3]);
}

extern "C" void kernel_launch(void* const* d_in, const int* in_sizes, int n_in,
                              void* d_out, int out_size, void* d_ws, size_t ws_size,
                              hipStream_t stream) {
    const float* img1 = (const float*)d_in[0];
    const float* img2 = (const float*)d_in[1];
    float* out = (float*)d_out;
    double* partial = (double*)d_ws;  // needs 16*96*8 = 12288 B of workspace

    const int planes = in_sizes[0] / (IMG_H * IMG_W);  // 32*3 = 96

    dim3 grid(NBX, planes);
    ssim_main_kernel<<<grid, 128, 0, stream>>>(img1, img2, partial);
    ssim_fin_kernel<<<1, 256, 0, stream>>>(partial, out, NBX * planes);
}